// Round 1
// baseline (550.046 us; speedup 1.0000x reference)
//
#include <hip/hip_runtime.h>

typedef float f32x4 __attribute__((ext_vector_type(4)));
typedef __bf16 bf16x8 __attribute__((ext_vector_type(8)));
typedef unsigned int u32x4 __attribute__((ext_vector_type(4)));
typedef unsigned short ushort_t;

// ---------------------------------------------------------------- fp32 -> bf16 (RNE)
__device__ __forceinline__ unsigned short f2bf(float f) {
    unsigned u = __float_as_uint(f);
    u += 0x7FFFu + ((u >> 16) & 1u);   // round-nearest-even (inputs are finite, no NaN path needed)
    return (unsigned short)(u >> 16);
}

__global__ __launch_bounds__(256) void cvt_f32_to_bf16(const f32x4* __restrict__ in,
                                                       u32x4* __restrict__ out) {
    long i = (long)blockIdx.x * 256 + threadIdx.x;   // one thread = 8 floats -> 16B store
    f32x4 a = in[2 * i];
    f32x4 b = in[2 * i + 1];
    u32x4 v;
    v.x = (unsigned)f2bf(a.x) | ((unsigned)f2bf(a.y) << 16);
    v.y = (unsigned)f2bf(a.z) | ((unsigned)f2bf(a.w) << 16);
    v.z = (unsigned)f2bf(b.x) | ((unsigned)f2bf(b.y) << 16);
    v.w = (unsigned)f2bf(b.z) | ((unsigned)f2bf(b.w) << 16);
    out[i] = v;
}

// ---------------------------------------------------------------- bf16 MFMA GEMM (B^T layout)
// out[m,n] = sum_k A[m,k]*B[n,k] + bias[n].  A:[M,K] bf16 row-major, B:[N,K] bf16 row-major.
// Block tile 128x128, BK=64, 4 waves (2x2), each wave 64x64 via 4x4 of 16x16x32 MFMA.
// LDS staged with global_load_lds width=16; XOR swizzle on 16B blocks: block kb of row r
// stored at column slot kb ^ (r&7)  -> ds_read_b128 spreads over all 8 bank-quads.
constexpr int KDIM = 4096;

__global__ __launch_bounds__(256) void gemm_bf16_mfma(const ushort_t* __restrict__ A,
                                                      const ushort_t* __restrict__ B,
                                                      const float* __restrict__ bias,
                                                      float* __restrict__ out) {
    __shared__ ushort_t As[128 * 64];   // 16 KB
    __shared__ ushort_t Bs[128 * 64];   // 16 KB

    const int tid  = threadIdx.x;
    const int lane = tid & 63;
    const int wave = tid >> 6;
    const int wm   = (wave >> 1) * 64;  // wave row offset in tile
    const int wn   = (wave & 1) * 64;   // wave col offset in tile
    const int q    = lane >> 4;         // quad 0..3
    const int ml   = lane & 15;

    const int m0 = blockIdx.y * 128;
    const int n0 = blockIdx.x * 128;

    // staging: load inst i, thread tid -> LDS 16B slot (i*256 + tid)
    //   row = i*32 + tid/8 ; stored slot col = tid&7 ; source block kb = (tid&7) ^ (row&7)
    const int srow = tid >> 3;
    const int kb   = (tid & 7) ^ (srow & 7);
    const ushort_t* ga = A + (size_t)(m0 + srow) * KDIM + kb * 8;
    const ushort_t* gb = B + (size_t)(n0 + srow) * KDIM + kb * 8;
    char* lAs = (char*)As;
    char* lBs = (char*)Bs;
    const int ldst = tid * 16;

    f32x4 acc[4][4];
#pragma unroll
    for (int i = 0; i < 4; ++i)
#pragma unroll
        for (int j = 0; j < 4; ++j) {
            acc[i][j].x = 0.f; acc[i][j].y = 0.f; acc[i][j].z = 0.f; acc[i][j].w = 0.f;
        }

    for (int k0 = 0; k0 < KDIM; k0 += 64) {
        __syncthreads();   // previous tile fully consumed
#pragma unroll
        for (int i = 0; i < 4; ++i)
            __builtin_amdgcn_global_load_lds(
                (const __attribute__((address_space(1))) unsigned int*)(ga + (size_t)i * 32 * KDIM + k0),
                (__attribute__((address_space(3))) unsigned int*)(lAs + i * 4096 + ldst),
                16, 0, 0);
#pragma unroll
        for (int i = 0; i < 4; ++i)
            __builtin_amdgcn_global_load_lds(
                (const __attribute__((address_space(1))) unsigned int*)(gb + (size_t)i * 32 * KDIM + k0),
                (__attribute__((address_space(3))) unsigned int*)(lBs + i * 4096 + ldst),
                16, 0, 0);
        __syncthreads();   // compiler emits vmcnt(0) drain here -> data visible

#pragma unroll
        for (int s = 0; s < 2; ++s) {   // two K=32 steps per BK=64 tile
            const int kbb = s * 4 + q;  // 16B block index along K for this quad
            const int sw  = (kbb ^ (ml & 7)) << 4;
            bf16x8 av[4], bv[4];
#pragma unroll
            for (int t = 0; t < 4; ++t) {
                const int row = wm + t * 16 + ml;      // row&7 == ml&7
                av[t] = *(const bf16x8*)(lAs + row * 128 + sw);
            }
#pragma unroll
            for (int t = 0; t < 4; ++t) {
                const int row = wn + t * 16 + ml;
                bv[t] = *(const bf16x8*)(lBs + row * 128 + sw);
            }
#pragma unroll
            for (int i = 0; i < 4; ++i)
#pragma unroll
                for (int j = 0; j < 4; ++j)
                    acc[i][j] = __builtin_amdgcn_mfma_f32_16x16x32_bf16(av[i], bv[j], acc[i][j], 0, 0, 0);
        }
    }

    // epilogue: C/D layout col=lane&15, row=q*4+reg
    float bb[4];
#pragma unroll
    for (int j = 0; j < 4; ++j) bb[j] = bias[n0 + wn + j * 16 + ml];

#pragma unroll
    for (int i = 0; i < 4; ++i) {
#pragma unroll
        for (int j = 0; j < 4; ++j) {
            const int gc = n0 + wn + j * 16 + ml;
#pragma unroll
            for (int r = 0; r < 4; ++r) {
                const int gr = m0 + wm + i * 16 + q * 4 + r;
                out[(size_t)gr * 4096 + gc] = acc[i][j][r] + bb[j];
            }
        }
    }
}

// ---------------------------------------------------------------- fp32 fallback (only if ws too small)
__global__ __launch_bounds__(256) void gemm_f32_fallback(const float* __restrict__ x,
                                                         const float* __restrict__ W,
                                                         const float* __restrict__ bias,
                                                         float* __restrict__ out) {
    __shared__ float As[32][33];
    __shared__ float Bs[32][33];
    const int tx = threadIdx.x & 31, ty = threadIdx.x >> 5;   // ty 0..7
    const int m0 = blockIdx.y * 32, n0 = blockIdx.x * 32;
    float acc[4] = {0.f, 0.f, 0.f, 0.f};
    for (int k0 = 0; k0 < 4096; k0 += 32) {
#pragma unroll
        for (int i = 0; i < 4; ++i) {
            As[ty + 8 * i][tx] = x[(size_t)(m0 + ty + 8 * i) * 4096 + k0 + tx];
            Bs[ty + 8 * i][tx] = W[(size_t)(n0 + ty + 8 * i) * 4096 + k0 + tx];
        }
        __syncthreads();
#pragma unroll 8
        for (int kk = 0; kk < 32; ++kk) {
            const float bv = Bs[tx][kk];
#pragma unroll
            for (int i = 0; i < 4; ++i) acc[i] += As[ty + 8 * i][kk] * bv;
        }
        __syncthreads();
    }
#pragma unroll
    for (int i = 0; i < 4; ++i)
        out[(size_t)(m0 + ty + 8 * i) * 4096 + n0 + tx] = acc[i] + bias[n0 + tx];
}

// ---------------------------------------------------------------- launch
extern "C" void kernel_launch(void* const* d_in, const int* in_sizes, int n_in,
                              void* d_out, int out_size, void* d_ws, size_t ws_size,
                              hipStream_t stream) {
    const float* x = (const float*)d_in[0];   // [8192, 4096]
    const float* W = (const float*)d_in[1];   // [4096, 4096]
    const float* b = (const float*)d_in[2];   // [4096]
    float* out = (float*)d_out;               // [8192, 4096]

    constexpr size_t T = 8192, DIN = 4096, DOUT = 4096;
    const size_t nx = T * DIN, nw = DOUT * DIN;

    if (ws_size >= (nx + nw) * sizeof(unsigned short)) {
        unsigned short* xbf = (unsigned short*)d_ws;
        unsigned short* wbf = xbf + nx;
        cvt_f32_to_bf16<<<(int)(nx / 8 / 256), 256, 0, stream>>>((const f32x4*)x, (u32x4*)xbf);
        cvt_f32_to_bf16<<<(int)(nw / 8 / 256), 256, 0, stream>>>((const f32x4*)W, (u32x4*)wbf);
        dim3 grid(DOUT / 128, T / 128);   // 32 x 64 = 2048 blocks
        gemm_bf16_mfma<<<grid, 256, 0, stream>>>(xbf, wbf, b, out);
    } else {
        dim3 grid(DOUT / 32, T / 32);
        gemm_f32_fallback<<<grid, 256, 0, stream>>>(x, W, b, out);
    }
}

// Round 2
// 510.282 us; speedup vs baseline: 1.0779x; 1.0779x over previous
//
#include <hip/hip_runtime.h>

typedef float f32x4 __attribute__((ext_vector_type(4)));
typedef __bf16 bf16x8 __attribute__((ext_vector_type(8)));
typedef unsigned int u32x4 __attribute__((ext_vector_type(4)));
typedef unsigned short ushort_t;

// ---------------------------------------------------------------- fp32 -> bf16 (RNE)
__device__ __forceinline__ unsigned short f2bf(float f) {
    unsigned u = __float_as_uint(f);
    u += 0x7FFFu + ((u >> 16) & 1u);   // round-nearest-even (inputs finite)
    return (unsigned short)(u >> 16);
}

// One fused cast kernel for both x and W.
//   x: 8192*4096 = 33554432 f32 -> 4194304 u32x4 outputs (threads 0 .. 4194303)
//   W: 4096*4096 = 16777216 f32 -> 2097152 u32x4 outputs (threads 4194304 .. 6291455)
// Split at thread 4194304 = block 16384 exactly -> wave-uniform branch, no divergence.
// Nontemporal loads: fp32 inputs are dead after this kernel; keep L2/L3 for the bf16
// outputs the GEMM is about to re-read.
__global__ __launch_bounds__(256) void cast_both(const f32x4* __restrict__ x, u32x4* __restrict__ xo,
                                                 const f32x4* __restrict__ w, u32x4* __restrict__ wo) {
    long t = (long)blockIdx.x * 256 + threadIdx.x;
    const f32x4* src;
    u32x4* dst;
    long j;
    if (t < 4194304L) { src = x; dst = xo; j = t; }
    else              { src = w; dst = wo; j = t - 4194304L; }
    f32x4 a = __builtin_nontemporal_load(&src[2 * j]);
    f32x4 b = __builtin_nontemporal_load(&src[2 * j + 1]);
    u32x4 v;
    v.x = (unsigned)f2bf(a.x) | ((unsigned)f2bf(a.y) << 16);
    v.y = (unsigned)f2bf(a.z) | ((unsigned)f2bf(a.w) << 16);
    v.z = (unsigned)f2bf(b.x) | ((unsigned)f2bf(b.y) << 16);
    v.w = (unsigned)f2bf(b.z) | ((unsigned)f2bf(b.w) << 16);
    dst[j] = v;   // cached store: GEMM re-reads this from L2/L3
}

// ---------------------------------------------------------------- bf16 MFMA GEMM (B^T layout)
// out[m,n] = sum_k A[m,k]*B[n,k] + bias[n].  A:[M,K] bf16 row-major, B:[N,K] bf16 row-major.
// Block tile 128x128, BK=64, 4 waves (2x2), each wave 64x64 via 4x4 of 16x16x32 MFMA.
// LDS staged with global_load_lds width=16; XOR swizzle on 16B blocks: block kb of row r
// stored at column slot kb ^ (r&7)  -> ds_read_b128 spreads over all 8 bank-quads.
// Verified R1: passes, 0 bank conflicts, ~845 TF (m97-structure plateau).
constexpr int KDIM = 4096;

__global__ __launch_bounds__(256) void gemm_bf16_mfma(const ushort_t* __restrict__ A,
                                                      const ushort_t* __restrict__ B,
                                                      const float* __restrict__ bias,
                                                      float* __restrict__ out) {
    __shared__ ushort_t As[128 * 64];   // 16 KB
    __shared__ ushort_t Bs[128 * 64];   // 16 KB

    const int tid  = threadIdx.x;
    const int lane = tid & 63;
    const int wave = tid >> 6;
    const int wm   = (wave >> 1) * 64;  // wave row offset in tile
    const int wn   = (wave & 1) * 64;   // wave col offset in tile
    const int q    = lane >> 4;         // quad 0..3
    const int ml   = lane & 15;

    const int m0 = blockIdx.y * 128;
    const int n0 = blockIdx.x * 128;

    // staging: load inst i, thread tid -> LDS 16B slot (i*256 + tid)
    //   row = i*32 + tid/8 ; stored slot col = tid&7 ; source block kb = (tid&7) ^ (row&7)
    const int srow = tid >> 3;
    const int kb   = (tid & 7) ^ (srow & 7);
    const ushort_t* ga = A + (size_t)(m0 + srow) * KDIM + kb * 8;
    const ushort_t* gb = B + (size_t)(n0 + srow) * KDIM + kb * 8;
    char* lAs = (char*)As;
    char* lBs = (char*)Bs;
    const int ldst = tid * 16;

    f32x4 acc[4][4];
#pragma unroll
    for (int i = 0; i < 4; ++i)
#pragma unroll
        for (int j = 0; j < 4; ++j) {
            acc[i][j].x = 0.f; acc[i][j].y = 0.f; acc[i][j].z = 0.f; acc[i][j].w = 0.f;
        }

    for (int k0 = 0; k0 < KDIM; k0 += 64) {
        __syncthreads();   // previous tile fully consumed
#pragma unroll
        for (int i = 0; i < 4; ++i)
            __builtin_amdgcn_global_load_lds(
                (const __attribute__((address_space(1))) unsigned int*)(ga + (size_t)i * 32 * KDIM + k0),
                (__attribute__((address_space(3))) unsigned int*)(lAs + i * 4096 + ldst),
                16, 0, 0);
#pragma unroll
        for (int i = 0; i < 4; ++i)
            __builtin_amdgcn_global_load_lds(
                (const __attribute__((address_space(1))) unsigned int*)(gb + (size_t)i * 32 * KDIM + k0),
                (__attribute__((address_space(3))) unsigned int*)(lBs + i * 4096 + ldst),
                16, 0, 0);
        __syncthreads();   // vmcnt(0) drain here -> data visible

#pragma unroll
        for (int s = 0; s < 2; ++s) {   // two K=32 steps per BK=64 tile
            const int kbb = s * 4 + q;  // 16B block index along K for this quad
            const int sw  = (kbb ^ (ml & 7)) << 4;
            bf16x8 av[4], bv[4];
#pragma unroll
            for (int t = 0; t < 4; ++t) {
                const int row = wm + t * 16 + ml;      // row&7 == ml&7
                av[t] = *(const bf16x8*)(lAs + row * 128 + sw);
            }
#pragma unroll
            for (int t = 0; t < 4; ++t) {
                const int row = wn + t * 16 + ml;
                bv[t] = *(const bf16x8*)(lBs + row * 128 + sw);
            }
#pragma unroll
            for (int i = 0; i < 4; ++i)
#pragma unroll
                for (int j = 0; j < 4; ++j)
                    acc[i][j] = __builtin_amdgcn_mfma_f32_16x16x32_bf16(av[i], bv[j], acc[i][j], 0, 0, 0);
        }
    }

    // epilogue: C/D layout col=lane&15, row=q*4+reg
    float bb[4];
#pragma unroll
    for (int j = 0; j < 4; ++j) bb[j] = bias[n0 + wn + j * 16 + ml];

#pragma unroll
    for (int i = 0; i < 4; ++i) {
#pragma unroll
        for (int j = 0; j < 4; ++j) {
            const int gc = n0 + wn + j * 16 + ml;
#pragma unroll
            for (int r = 0; r < 4; ++r) {
                const int gr = m0 + wm + i * 16 + q * 4 + r;
                out[(size_t)gr * 4096 + gc] = acc[i][j][r] + bb[j];
            }
        }
    }
}

// ---------------------------------------------------------------- fp32 fallback (only if ws too small)
__global__ __launch_bounds__(256) void gemm_f32_fallback(const float* __restrict__ x,
                                                         const float* __restrict__ W,
                                                         const float* __restrict__ bias,
                                                         float* __restrict__ out) {
    __shared__ float As[32][33];
    __shared__ float Bs[32][33];
    const int tx = threadIdx.x & 31, ty = threadIdx.x >> 5;   // ty 0..7
    const int m0 = blockIdx.y * 32, n0 = blockIdx.x * 32;
    float acc[4] = {0.f, 0.f, 0.f, 0.f};
    for (int k0 = 0; k0 < 4096; k0 += 32) {
#pragma unroll
        for (int i = 0; i < 4; ++i) {
            As[ty + 8 * i][tx] = x[(size_t)(m0 + ty + 8 * i) * 4096 + k0 + tx];
            Bs[ty + 8 * i][tx] = W[(size_t)(n0 + ty + 8 * i) * 4096 + k0 + tx];
        }
        __syncthreads();
#pragma unroll 8
        for (int kk = 0; kk < 32; ++kk) {
            const float bv = Bs[tx][kk];
#pragma unroll
            for (int i = 0; i < 4; ++i) acc[i] += As[ty + 8 * i][kk] * bv;
        }
        __syncthreads();
    }
#pragma unroll
    for (int i = 0; i < 4; ++i)
        out[(size_t)(m0 + ty + 8 * i) * 4096 + n0 + tx] = acc[i] + bias[n0 + tx];
}

// ---------------------------------------------------------------- launch
extern "C" void kernel_launch(void* const* d_in, const int* in_sizes, int n_in,
                              void* d_out, int out_size, void* d_ws, size_t ws_size,
                              hipStream_t stream) {
    const float* x = (const float*)d_in[0];   // [8192, 4096]
    const float* W = (const float*)d_in[1];   // [4096, 4096]
    const float* b = (const float*)d_in[2];   // [4096]
    float* out = (float*)d_out;               // [8192, 4096]

    constexpr size_t T = 8192, DIN = 4096, DOUT = 4096;
    const size_t nx = T * DIN, nw = DOUT * DIN;

    if (ws_size >= (nx + nw) * sizeof(unsigned short)) {
        unsigned short* xbf = (unsigned short*)d_ws;
        unsigned short* wbf = xbf + nx;
        // total threads = nx/8 + nw/8 = 6291456 -> 24576 blocks of 256
        cast_both<<<24576, 256, 0, stream>>>((const f32x4*)x, (u32x4*)xbf,
                                             (const f32x4*)W, (u32x4*)wbf);
        dim3 grid(DOUT / 128, T / 128);   // 32 x 64 = 2048 blocks
        gemm_bf16_mfma<<<grid, 256, 0, stream>>>(xbf, wbf, b, out);
    } else {
        dim3 grid(DOUT / 32, T / 32);
        gemm_f32_fallback<<<grid, 256, 0, stream>>>(x, W, b, out);
    }
}